// Round 1
// baseline (18251.108 us; speedup 1.0000x reference)
//
#include <hip/hip_runtime.h>
#include <math.h>

// LSTM: B=256, S=512, I=64, H=256, fp32.
// Batch-partitioned persistent kernel: 64 blocks x 1024 threads.
// Each block owns R=4 batch rows for all 512 steps (recurrence is
// independent per batch row -> no inter-block sync needed).
// Wave w of 16: r = w>>2 (row), g = w&3 (gate: 0=i,1=f,2=c,3=o).
// Each wave computes its gate's 256 pre-activations for its row as a
// 320-long dot product over [h(256) ; x(64)] vs [U(256xH) ; W(64xH)].

#define BB 256
#define SS 512
#define II 64
#define HH 256
#define RR 4
#define NBLK (BB / RR)   // 64

__device__ __forceinline__ float fast_sigmoid(float v) {
    // safe: __expf(-v) overflows only for v < -88; preacts bounded ~ +-35
    float e = __expf(-v);
    return __builtin_amdgcn_rcpf(1.0f + e);
}

__device__ __forceinline__ float fast_tanh(float v) {
    v = fminf(fmaxf(v, -15.0f), 15.0f);          // avoid inf/inf
    float e = __expf(2.0f * v);
    return (e - 1.0f) * __builtin_amdgcn_rcpf(e + 1.0f);
}

__global__ __launch_bounds__(1024, 1)
void lstm_persistent(const float* __restrict__ x,
                     const float* __restrict__ wi, const float* __restrict__ ui, const float* __restrict__ bi,
                     const float* __restrict__ wf, const float* __restrict__ uf, const float* __restrict__ bf,
                     const float* __restrict__ wc, const float* __restrict__ uc, const float* __restrict__ bc,
                     const float* __restrict__ wo, const float* __restrict__ uo, const float* __restrict__ bo,
                     float* __restrict__ out)
{
    __shared__ float hx[RR][320];         // [r][0..255]=h, [r][256..319]=x_s
    __shared__ float act[4][RR][HH];      // activated gates
    __shared__ float cst[RR][HH];         // cell state

    const int tid  = threadIdx.x;
    const int wave = tid >> 6;
    const int lane = tid & 63;
    const int r    = wave >> 2;           // 0..3
    const int g    = wave & 3;            // 0..3
    const int c0   = lane * 4;            // 4 consecutive gate-columns per lane

    const int b0 = blockIdx.x * RR;

    const float* Ug = (g == 0) ? ui : (g == 1) ? uf : (g == 2) ? uc : uo;
    const float* Wg = (g == 0) ? wi : (g == 1) ? wf : (g == 2) ? wc : wo;
    const float* Bg = (g == 0) ? bi : (g == 1) ? bf : (g == 2) ? bc : bo;

    const float4 bias = *reinterpret_cast<const float4*>(Bg + c0);

    // init: h = 0, c = 0, load x for s = 0
    {
        int rr2 = tid >> 8, cc = tid & 255;      // 1024 threads cover R x 256
        hx[rr2][cc]  = 0.0f;
        cst[rr2][cc] = 0.0f;
        if (tid < RR * II) {
            int rr = tid >> 6, ii = tid & 63;
            hx[rr][256 + ii] = x[(size_t)(b0 + rr) * (SS * II) + ii];
        }
    }
    __syncthreads();

    for (int s = 0; s < SS; ++s) {
        // ---- gate pre-activation: bias + sum_k hx[r][k] * M[k][col] ----
        float a0 = bias.x, a1 = bias.y, a2 = bias.z, a3 = bias.w;

        #pragma unroll 8
        for (int k = 0; k < HH; ++k) {
            const float hv = hx[r][k];                                   // LDS broadcast
            const float4 u = *reinterpret_cast<const float4*>(Ug + (size_t)k * HH + c0);
            a0 = fmaf(hv, u.x, a0);
            a1 = fmaf(hv, u.y, a1);
            a2 = fmaf(hv, u.z, a2);
            a3 = fmaf(hv, u.w, a3);
        }
        #pragma unroll 8
        for (int k = 0; k < II; ++k) {
            const float xv = hx[r][256 + k];
            const float4 w = *reinterpret_cast<const float4*>(Wg + (size_t)k * HH + c0);
            a0 = fmaf(xv, w.x, a0);
            a1 = fmaf(xv, w.y, a1);
            a2 = fmaf(xv, w.z, a2);
            a3 = fmaf(xv, w.w, a3);
        }

        float4 av;
        if (g == 2) {
            av.x = fast_tanh(a0); av.y = fast_tanh(a1);
            av.z = fast_tanh(a2); av.w = fast_tanh(a3);
        } else {
            av.x = fast_sigmoid(a0); av.y = fast_sigmoid(a1);
            av.z = fast_sigmoid(a2); av.w = fast_sigmoid(a3);
        }
        *reinterpret_cast<float4*>(&act[g][r][c0]) = av;
        __syncthreads();

        // ---- elementwise cell update: 1 value per thread ----
        {
            const int r2 = tid >> 8, cc = tid & 255;
            const float iv = act[0][r2][cc];
            const float fv = act[1][r2][cc];
            const float gv = act[2][r2][cc];
            const float ov = act[3][r2][cc];
            const float cnew = fmaf(fv, cst[r2][cc], iv * gv);
            const float hnew = ov * fast_tanh(cnew);
            cst[r2][cc] = cnew;
            hx[r2][cc]  = hnew;
            out[(size_t)s * (BB * HH) + (size_t)(b0 + r2) * HH + cc] = hnew;
            if (s == SS - 1) {
                out[(size_t)SS * BB * HH + (size_t)(b0 + r2) * HH + cc] = hnew;
                out[(size_t)SS * BB * HH + (size_t)BB * HH + (size_t)(b0 + r2) * HH + cc] = cnew;
            }
        }
        // ---- prefetch next x ----
        if (s + 1 < SS && tid < RR * II) {
            int rr = tid >> 6, ii = tid & 63;
            hx[rr][256 + ii] = x[(size_t)(b0 + rr) * (SS * II) + (size_t)(s + 1) * II + ii];
        }
        __syncthreads();
    }
}

extern "C" void kernel_launch(void* const* d_in, const int* in_sizes, int n_in,
                              void* d_out, int out_size, void* d_ws, size_t ws_size,
                              hipStream_t stream) {
    const float* x  = (const float*)d_in[0];
    const float* wi = (const float*)d_in[1];
    const float* ui = (const float*)d_in[2];
    const float* bi = (const float*)d_in[3];
    const float* wf = (const float*)d_in[4];
    const float* uf = (const float*)d_in[5];
    const float* bf = (const float*)d_in[6];
    const float* wc = (const float*)d_in[7];
    const float* uc = (const float*)d_in[8];
    const float* bc = (const float*)d_in[9];
    const float* wo = (const float*)d_in[10];
    const float* uo = (const float*)d_in[11];
    const float* bo = (const float*)d_in[12];
    float* out = (float*)d_out;

    lstm_persistent<<<NBLK, 1024, 0, stream>>>(
        x, wi, ui, bi, wf, uf, bf, wc, uc, bc, wo, uo, bo, out);
}

// Round 4
// 13211.092 us; speedup vs baseline: 1.3815x; 1.3815x over previous
//
#include <hip/hip_runtime.h>
#include <math.h>

// LSTM: B=256, S=512, I=64, H=256, fp32.
//
// Cooperative design (R4): 256 blocks = 32 row-groups x 8 col-blocks.
// Weights live in REGISTERS (40 VGPR/lane), eliminating the per-CU L2-port
// wall (~141 GB/s/CU measured in R1) that caps any batch-partitioned
// variant at ~8.9 us/step. A row-group = 8 blocks that exchange their
// 8 h-rows each step through d_ws using a release/acquire flag barrier
// (agent scope -> cross-XCD safe; one barrier/step; h double-buffered).
//   block -> (group, cb): xcd = blk&7, inner = blk>>3,
//                         group = xcd*4 + (inner&3), cb = inner>>2
//   (keeps a group's 8 blocks on one XCD under the %8 dispatch heuristic;
//    agent-scope atomics keep it correct regardless of placement.)
// Within a block (16 waves x 64 lanes):
//   wave wv owns k-slice [20*wv, 20*wv+20) of [h(256); x(64)]
//   lane owns gate-cols gc0 = lane (gates i/f) and gc1 = 64+lane (gates c/o),
//     col = c0 + (lane&31)   [gc layout: gate*32 + colIdx]
//   partial dots accumulated across waves via LDS atomicAdd (stride-4B,
//   2-way banking = free) into preact[8][128].
// Residency: LDS ~19.5 KB, VGPR <= 128 (launch_bounds 1024x4), grid = 256
// = CU count -> all blocks schedulable; no deadlock.

#define BB 256
#define SS 512
#define II 64
#define HH 256
#define KTOT (HH + II)          // 320
#define NWAVE 16
#define KPW (KTOT / NWAVE)      // 20
#define RPG 8                   // rows per group
#define NGROUP (BB / RPG)       // 32
#define CBPG 8                  // col-blocks per group
#define HCPB (HH / CBPG)        // 32 hidden cols per block
#define NBLK (NGROUP * CBPG)    // 256

#define WS_NEEDED (2 * BB * HH * 4 + NBLK * 4)   // h double-buffer + flags

__device__ __forceinline__ float fast_sigmoid(float v) {
    float e = __expf(-v);
    return __builtin_amdgcn_rcpf(1.0f + e);
}

__device__ __forceinline__ float fast_tanh(float v) {
    v = fminf(fmaxf(v, -15.0f), 15.0f);
    float e = __expf(2.0f * v);
    return (e - 1.0f) * __builtin_amdgcn_rcpf(e + 1.0f);
}

__global__ __launch_bounds__(1024, 4)
void lstm_coop(const float* __restrict__ x,
               const float* __restrict__ wi, const float* __restrict__ ui, const float* __restrict__ bi,
               const float* __restrict__ wf, const float* __restrict__ uf, const float* __restrict__ bf,
               const float* __restrict__ wc, const float* __restrict__ uc, const float* __restrict__ bc,
               const float* __restrict__ wo, const float* __restrict__ uo, const float* __restrict__ bo,
               float* __restrict__ out, float* __restrict__ hglob, int* __restrict__ flags)
{
    __shared__ __align__(16) float hx[RPG][KTOT];       // 10 KB: [r][0:256)=h, [256:320)=x_s
    __shared__ __align__(16) float preact[RPG][128];    // 4 KB (atomic-accumulated)
    __shared__ __align__(16) float act[RPG][128];       // 4 KB (gc = gate*32+colIdx)
    __shared__ __align__(16) float cst[RPG][HCPB];      // 1 KB

    const int tid  = threadIdx.x;
    const int wv   = tid >> 6;
    const int lane = tid & 63;

    const int blk   = blockIdx.x;
    const int xcd   = blk & 7;
    const int inner = blk >> 3;                  // 0..31
    const int group = xcd * 4 + (inner & 3);     // 0..31
    const int cb    = inner >> 2;                // 0..7
    const int b0 = group * RPG;
    const int c0 = cb * HCPB;

    // this lane's two gate-columns
    const int col   = c0 + (lane & 31);
    const int gsel  = lane >> 5;                 // 0 or 1
    const float* U0 = gsel ? uf : ui;            // gc0: gate i or f
    const float* W0 = gsel ? wf : wi;
    const float* U1 = gsel ? uo : uc;            // gc1: gate c or o
    const float* W1 = gsel ? wo : wc;

    // ---- preload this wave's k-slice of [U;W] into registers ----
    const int k0 = wv * KPW;
    float wreg0[KPW], wreg1[KPW];
    #pragma unroll
    for (int j = 0; j < KPW; ++j) {
        const int k = k0 + j;                    // wave-uniform branch
        if (k < HH) {
            wreg0[j] = U0[(size_t)k * HH + col];
            wreg1[j] = U1[(size_t)k * HH + col];
        } else {
            wreg0[j] = W0[(size_t)(k - HH) * HH + col];
            wreg1[j] = W1[(size_t)(k - HH) * HH + col];
        }
    }

    // activation-phase identity for this thread (fixed across steps)
    const int r_a   = tid >> 7;                  // 0..7
    const int gc_a  = tid & 127;                 // gate*32 + colIdx
    const int gate_a = gc_a >> 5;
    {
    }
    const float* Ba = (gate_a == 0) ? bi : (gate_a == 1) ? bf : (gate_a == 2) ? bc : bo;
    const float abias = Ba[c0 + (gc_a & 31)];

    // ---- init: h=0, c=0, preact=0, x(0) ----
    {
        if (tid < 512) {                         // zero h-part of hx
            const int r = tid >> 6, c4 = (tid & 63) * 4;
            *reinterpret_cast<float4*>(&hx[r][c4]) = make_float4(0.f, 0.f, 0.f, 0.f);
        } else if (tid < 640) {                  // x for s=0
            const int t = tid - 512;
            const int r = t >> 4, i4 = (t & 15) * 4;
            *reinterpret_cast<float4*>(&hx[r][HH + i4]) =
                *reinterpret_cast<const float4*>(&x[(size_t)(b0 + r) * (SS * II) + i4]);
        }
        (&preact[0][0])[tid] = 0.0f;
        if (tid < RPG * HCPB) (&cst[0][0])[tid] = 0.0f;
    }
    __syncthreads();

    for (int s = 0; s < SS; ++s) {
        // ---- partial dots: 8 rows x 2 gate-cols, k-slice from regs ----
        float acc0[RPG], acc1[RPG];
        #pragma unroll
        for (int r = 0; r < RPG; ++r) { acc0[r] = 0.0f; acc1[r] = 0.0f; }
        #pragma unroll
        for (int r = 0; r < RPG; ++r) {
            #pragma unroll
            for (int q = 0; q < KPW / 4; ++q) {
                const float4 hv = *reinterpret_cast<const float4*>(&hx[r][k0 + q * 4]);
                acc0[r] = fmaf(wreg0[q * 4 + 0], hv.x, acc0[r]);
                acc0[r] = fmaf(wreg0[q * 4 + 1], hv.y, acc0[r]);
                acc0[r] = fmaf(wreg0[q * 4 + 2], hv.z, acc0[r]);
                acc0[r] = fmaf(wreg0[q * 4 + 3], hv.w, acc0[r]);
                acc1[r] = fmaf(wreg1[q * 4 + 0], hv.x, acc1[r]);
                acc1[r] = fmaf(wreg1[q * 4 + 1], hv.y, acc1[r]);
                acc1[r] = fmaf(wreg1[q * 4 + 2], hv.z, acc1[r]);
                acc1[r] = fmaf(wreg1[q * 4 + 3], hv.w, acc1[r]);
            }
        }
        #pragma unroll
        for (int r = 0; r < RPG; ++r) {
            atomicAdd(&preact[r][lane], acc0[r]);        // gc0 = lane
            atomicAdd(&preact[r][64 + lane], acc1[r]);   // gc1 = 64+lane
        }
        __syncthreads();                                   // (A)

        // ---- activation ----
        {
            const float v = preact[r_a][gc_a] + abias;
            const float a = (gate_a == 2) ? fast_tanh(v) : fast_sigmoid(v);
            act[r_a][gc_a] = a;
            preact[r_a][gc_a] = 0.0f;                      // reset for next step
        }
        __syncthreads();                                   // (B)

        // ---- cell update (tid<256) + x prefetch (256<=tid<384) ----
        if (tid < 256) {
            const int r = tid >> 5, h = tid & 31;
            const float iv = act[r][h];
            const float fv = act[r][32 + h];
            const float gv = act[r][64 + h];
            const float ov = act[r][96 + h];
            const float cnew = fmaf(fv, cst[r][h], iv * gv);
            const float hnew = ov * fast_tanh(cnew);
            cst[r][h] = cnew;
            const size_t orow = (size_t)(b0 + r) * HH + (size_t)(c0 + h);
            out[(size_t)s * (BB * HH) + orow] = hnew;
            hglob[(size_t)(s & 1) * (BB * HH) + orow] = hnew;
            if (s == SS - 1) {
                out[(size_t)SS * BB * HH + orow] = hnew;
                out[(size_t)SS * BB * HH + (size_t)BB * HH + orow] = cnew;
            }
        } else if (tid < 384 && s + 1 < SS) {
            const int t = tid - 256;
            const int r = t >> 4, i4 = (t & 15) * 4;
            *reinterpret_cast<float4*>(&hx[r][HH + i4]) =
                *reinterpret_cast<const float4*>(
                    &x[(size_t)(b0 + r) * (SS * II) + (size_t)(s + 1) * II + i4]);
        }

        if (s + 1 < SS) {
            __syncthreads();                               // (C) all writes drained
            if (tid == 0) {
                __hip_atomic_store(&flags[group * CBPG + cb], s + 1,
                                   __ATOMIC_RELEASE, __HIP_MEMORY_SCOPE_AGENT);
            }
            if (wv == 0) {
                // wave 0 polls the group's 8 flags (monotone counters; the
                // 0xAA poison is negative as int -> first barrier can't
                // false-pass). Other waves park at (D).
                const int fi = group * CBPG + (lane & 7);
                const int target = s + 1;
                while (true) {
                    const int fv2 = __hip_atomic_load(&flags[fi], __ATOMIC_RELAXED,
                                                      __HIP_MEMORY_SCOPE_AGENT);
                    if (__all(fv2 >= target)) break;
                    __builtin_amdgcn_s_sleep(1);
                }
                // acquire: invalidate L1/L2 so the h reload below sees the
                // peers' hglob stores (cross-XCD safe)
                (void)__hip_atomic_load(&flags[fi], __ATOMIC_ACQUIRE,
                                        __HIP_MEMORY_SCOPE_AGENT);
            }
            __syncthreads();                               // (D)
            if (tid < 512) {                               // reload 8 x 256 h slab
                const int r = tid >> 6, c4 = (tid & 63) * 4;
                *reinterpret_cast<float4*>(&hx[r][c4]) =
                    *reinterpret_cast<const float4*>(
                        &hglob[(size_t)(s & 1) * (BB * HH) + (size_t)(b0 + r) * HH + c4]);
            }
            __syncthreads();                               // (E)
        }
    }
}

// ---------------- fallback (R2 batch-partitioned) if ws too small ----------------

#define RR 4
#define NBLK_BP (BB / RR)

__global__ __launch_bounds__(1024, 1)
void lstm_batchpart(const float* __restrict__ x,
                    const float* __restrict__ wi, const float* __restrict__ ui, const float* __restrict__ bi,
                    const float* __restrict__ wf, const float* __restrict__ uf, const float* __restrict__ bf,
                    const float* __restrict__ wc, const float* __restrict__ uc, const float* __restrict__ bc,
                    const float* __restrict__ wo, const float* __restrict__ uo, const float* __restrict__ bo,
                    float* __restrict__ out)
{
    __shared__ float hx[RR][320];
    __shared__ float act[4][RR][HH];
    __shared__ float cst[RR][HH];

    const int tid  = threadIdx.x;
    const int wave = tid >> 6;
    const int lane = tid & 63;
    const int g    = wave & 3;
    const int cg   = wave >> 2;
    const int c    = cg * 64 + lane;
    const int b0 = blockIdx.x * RR;

    const float* Ug = (g == 0) ? ui : (g == 1) ? uf : (g == 2) ? uc : uo;
    const float* Wg = (g == 0) ? wi : (g == 1) ? wf : (g == 2) ? wc : wo;
    const float* Bg = (g == 0) ? bi : (g == 1) ? bf : (g == 2) ? bc : bo;
    const float bias_c = Bg[c];

    {
        int rr2 = tid >> 8, cc = tid & 255;
        hx[rr2][cc]  = 0.0f;
        cst[rr2][cc] = 0.0f;
        if (tid < RR * II) {
            int rr = tid >> 6, ii = tid & 63;
            hx[rr][256 + ii] = x[(size_t)(b0 + rr) * (SS * II) + ii];
        }
    }
    __syncthreads();

    for (int s = 0; s < SS; ++s) {
        float a0 = bias_c, a1 = bias_c, a2 = bias_c, a3 = bias_c;
        #pragma unroll 2
        for (int k = 0; k < HH; k += 4) {
            const float4 h0 = *reinterpret_cast<const float4*>(&hx[0][k]);
            const float4 h1 = *reinterpret_cast<const float4*>(&hx[1][k]);
            const float4 h2 = *reinterpret_cast<const float4*>(&hx[2][k]);
            const float4 h3 = *reinterpret_cast<const float4*>(&hx[3][k]);
            const float w0 = Ug[(size_t)(k + 0) * HH + c];
            const float w1 = Ug[(size_t)(k + 1) * HH + c];
            const float w2 = Ug[(size_t)(k + 2) * HH + c];
            const float w3 = Ug[(size_t)(k + 3) * HH + c];
            a0 = fmaf(w0, h0.x, a0); a0 = fmaf(w1, h0.y, a0);
            a0 = fmaf(w2, h0.z, a0); a0 = fmaf(w3, h0.w, a0);
            a1 = fmaf(w0, h1.x, a1); a1 = fmaf(w1, h1.y, a1);
            a1 = fmaf(w2, h1.z, a1); a1 = fmaf(w3, h1.w, a1);
            a2 = fmaf(w0, h2.x, a2); a2 = fmaf(w1, h2.y, a2);
            a2 = fmaf(w2, h2.z, a2); a2 = fmaf(w3, h2.w, a2);
            a3 = fmaf(w0, h3.x, a3); a3 = fmaf(w1, h3.y, a3);
            a3 = fmaf(w2, h3.z, a3); a3 = fmaf(w3, h3.w, a3);
        }
        #pragma unroll 2
        for (int k = 0; k < II; k += 4) {
            const float4 h0 = *reinterpret_cast<const float4*>(&hx[0][256 + k]);
            const float4 h1 = *reinterpret_cast<const float4*>(&hx[1][256 + k]);
            const float4 h2 = *reinterpret_cast<const float4*>(&hx[2][256 + k]);
            const float4 h3 = *reinterpret_cast<const float4*>(&hx[3][256 + k]);
            const float w0 = Wg[(size_t)(k + 0) * HH + c];
            const float w1 = Wg[(size_t)(k + 1) * HH + c];
            const float w2 = Wg[(size_t)(k + 2) * HH + c];
            const float w3 = Wg[(size_t)(k + 3) * HH + c];
            a0 = fmaf(w0, h0.x, a0); a0 = fmaf(w1, h0.y, a0);
            a0 = fmaf(w2, h0.z, a0); a0 = fmaf(w3, h0.w, a0);
            a1 = fmaf(w0, h1.x, a1); a1 = fmaf(w1, h1.y, a1);
            a1 = fmaf(w2, h1.z, a1); a1 = fmaf(w3, h1.w, a1);
            a2 = fmaf(w0, h2.x, a2); a2 = fmaf(w1, h2.y, a2);
            a2 = fmaf(w2, h2.z, a2); a2 = fmaf(w3, h2.w, a2);
            a3 = fmaf(w0, h3.x, a3); a3 = fmaf(w1, h3.y, a3);
            a3 = fmaf(w2, h3.z, a3); a3 = fmaf(w3, h3.w, a3);
        }

        float v0, v1, v2, v3;
        if (g == 2) {
            v0 = fast_tanh(a0); v1 = fast_tanh(a1);
            v2 = fast_tanh(a2); v3 = fast_tanh(a3);
        } else {
            v0 = fast_sigmoid(a0); v1 = fast_sigmoid(a1);
            v2 = fast_sigmoid(a2); v3 = fast_sigmoid(a3);
        }
        act[g][0][c] = v0;
        act[g][1][c] = v1;
        act[g][2][c] = v2;
        act[g][3][c] = v3;
        __syncthreads();

        {
            const int r2 = tid >> 8, cc = tid & 255;
            const float iv = act[0][r2][cc];
            const float fv = act[1][r2][cc];
            const float gv = act[2][r2][cc];
            const float ov = act[3][r2][cc];
            const float cnew = fmaf(fv, cst[r2][cc], iv * gv);
            const float hnew = ov * fast_tanh(cnew);
            cst[r2][cc] = cnew;
            hx[r2][cc]  = hnew;
            out[(size_t)s * (BB * HH) + (size_t)(b0 + r2) * HH + cc] = hnew;
            if (s == SS - 1) {
                out[(size_t)SS * BB * HH + (size_t)(b0 + r2) * HH + cc] = hnew;
                out[(size_t)SS * BB * HH + (size_t)BB * HH + (size_t)(b0 + r2) * HH + cc] = cnew;
            }
        }
        if (s + 1 < SS && tid < RR * II) {
            int rr = tid >> 6, ii = tid & 63;
            hx[rr][256 + ii] = x[(size_t)(b0 + rr) * (SS * II) + (size_t)(s + 1) * II + ii];
        }
        __syncthreads();
    }
}

extern "C" void kernel_launch(void* const* d_in, const int* in_sizes, int n_in,
                              void* d_out, int out_size, void* d_ws, size_t ws_size,
                              hipStream_t stream) {
    const float* x  = (const float*)d_in[0];
    const float* wi = (const float*)d_in[1];
    const float* ui = (const float*)d_in[2];
    const float* bi = (const float*)d_in[3];
    const float* wf = (const float*)d_in[4];
    const float* uf = (const float*)d_in[5];
    const float* bf = (const float*)d_in[6];
    const float* wc = (const float*)d_in[7];
    const float* uc = (const float*)d_in[8];
    const float* bc = (const float*)d_in[9];
    const float* wo = (const float*)d_in[10];
    const float* uo = (const float*)d_in[11];
    const float* bo = (const float*)d_in[12];
    float* out = (float*)d_out;

    if (ws_size >= (size_t)WS_NEEDED) {
        float* hglob = (float*)d_ws;                       // 2 x B x H
        int*   flags = (int*)((char*)d_ws + (size_t)2 * BB * HH * 4);
        lstm_coop<<<NBLK, 1024, 0, stream>>>(
            x, wi, ui, bi, wf, uf, bf, wc, uc, bc, wo, uo, bo, out, hglob, flags);
    } else {
        lstm_batchpart<<<NBLK_BP, 1024, 0, stream>>>(
            x, wi, ui, bi, wf, uf, bf, wc, uc, bc, wo, uo, bo, out);
    }
}